// Round 3
// baseline (126.035 us; speedup 1.0000x reference)
//
#include <hip/hip_runtime.h>

constexpr int B = 64, N = 8732, C = 21, M = 16;
constexpr int TROW = 1 + 6 * M;        // 97
constexpr int NB16 = 65536;            // 16-bit key bins
constexpr int NREP = 4;                // histogram replicas (contention spread)
constexpr float FSCALE = 262144.0f;    // 2^18 fixed-point scale for CE sums
constexpr unsigned long long CNT1 = 1ull << 44;  // count field increment
constexpr unsigned long long FIXMASK = (1ull << 44) - 1;

struct Ctl {
  unsigned pnum, validCount;
  float posCE, bboxNum;
};

__device__ __forceinline__ unsigned f2key(float f) {
  unsigned u = __float_as_uint(f);
  return (u & 0x80000000u) ? ~u : (u | 0x80000000u);
}
__device__ __forceinline__ float key2f(unsigned k) {
  unsigned u = (k & 0x80000000u) ? (k ^ 0x80000000u) : ~k;
  return __uint_as_float(u);
}

// ---- zero hist replicas + ctl ----
__global__ __launch_bounds__(256) void k_zero(unsigned long long* __restrict__ hist,
                                              Ctl* __restrict__ ctl) {
  int idx = blockIdx.x * 256 + threadIdx.x;       // 512 blocks * 256 = 131072
  hist[idx * 2] = 0ull;
  hist[idx * 2 + 1] = 0ull;                        // 262144 u64 total = NREP*NB16
  if (idx == 0) {
    ctl->pnum = 0; ctl->validCount = 0;
    ctl->posCE = 0.f; ctl->bboxNum = 0.f;
  }
}

// ---- main: logp0 per anchor -> u64 hist atomic; fused target processing ----
__global__ __launch_bounds__(256) void k_main(
    const float* __restrict__ conf, const float* __restrict__ bbox,
    const float* __restrict__ target, const float* __restrict__ pred,
    unsigned long long* __restrict__ hist, Ctl* __restrict__ ctl) {
  __shared__ __align__(16) float srow[256 * C];
  __shared__ int sk[M];
  int b = blockIdx.y;
  int n0 = blockIdx.x * 256;
  int tid = threadIdx.x;

  const float* tr = target + (size_t)b * TROW;
  if (tid < M) {
    int num = (int)tr[0];
    int k = (int)tr[1 + 6 * tid + 5];
    sk[tid] = (tid < num) ? k : -1;
  }
  __syncthreads();

  int rows = min(256, N - n0);
  const float* gbase = conf + ((size_t)b * N + n0) * C;
  if (rows == 256) {
    const float4* g4 = (const float4*)gbase;
    float4* s4 = (float4*)srow;
    for (int i = tid; i < 256 * C / 4; i += 256) s4[i] = g4[i];
  } else {
    int nflt = rows * C;
    for (int i = tid; i < nflt; i += 256) srow[i] = gbase[i];
  }
  __syncthreads();

  unsigned long long* myh = hist + ((size_t)((blockIdx.x + blockIdx.y) & (NREP - 1)) << 16);
  if (tid < rows) {
    int n = n0 + tid;
    const float* x = srow + tid * C;
    float mx = x[0];
    for (int c = 1; c < C; c++) mx = fmaxf(mx, x[c]);
    float s = 0.f;
    for (int c = 0; c < C; c++) s += __expf(x[c] - mx);
    float logp0 = x[0] - mx - __logf(s);
    bool assigned = false;
    for (int j = 0; j < M; j++) assigned |= (sk[j] == n);
    if (!assigned) {
      unsigned key16 = f2key(logp0) >> 16;
      float ce = -logp0;
      unsigned long long inc = CNT1 | (unsigned long long)(ce * FSCALE + 0.5f);
      atomicAdd(&myh[key16], inc);
    }
  }

  // fused per-batch target processing (block x==0 of each batch row)
  if (blockIdx.x == 0 && tid < M && sk[tid] >= 0) {
    const float* e = tr + 1 + 6 * tid;
    int cls = (int)e[0];
    float tx1 = e[1], ty1 = e[2], tx2 = e[3], ty2 = e[4];
    int k = sk[tid];
    float p0 = pred[k * 4 + 0], p1 = pred[k * 4 + 1];
    float p2 = pred[k * 4 + 2], p3 = pred[k * 4 + 3];
    float pw = p2 - p0, ph = p3 - p1;
    float pcx = (p0 + p2) * 0.5f, pcy = (p1 + p3) * 0.5f;
    float tw = tx2 - tx1, th = ty2 - ty1;
    float tcx = (tx1 + tx2) * 0.5f, tcy = (ty1 + ty2) * 0.5f;
    float ebv[4];
    ebv[0] = (tcx - pcx) / pw;
    ebv[1] = (tcy - pcy) / ph;
    ebv[2] = __logf(tw / pw);
    ebv[3] = __logf(th / ph);
    const float* bo = bbox + ((size_t)b * N + k) * 4;
    float sl = 0.f;
    for (int j = 0; j < 4; j++) {
      float d = bo[j] - ebv[j];
      float ad = fabsf(d);
      sl += (ad < 1.f) ? 0.5f * d * d : ad - 0.5f;
    }
    atomicAdd(&ctl->bboxNum, sl);
    atomicAdd(&ctl->validCount, 1u);
    if (cls > 0) {
      atomicAdd(&ctl->pnum, 1u);
      const float* x = conf + ((size_t)b * N + k) * C;
      float mx = x[0];
      for (int c = 1; c < C; c++) mx = fmaxf(mx, x[c]);
      float s = 0.f;
      for (int c = 0; c < C; c++) s += __expf(x[c] - mx);
      float lp = x[cls] - mx - __logf(s);
      atomicAdd(&ctl->posCE, -lp);
    }
  }
}

// ---- merge replicas; per-block (1024-bin) packed totals ----
__global__ __launch_bounds__(256) void k_merge(
    const unsigned long long* __restrict__ hist,
    unsigned long long* __restrict__ merged,
    unsigned long long* __restrict__ blockTot) {
  int blk = blockIdx.x, tid = threadIdx.x;
  int base = blk * 1024 + tid * 4;
  unsigned long long local = 0;
  for (int j = 0; j < 4; j++) {
    int bin = base + j;
    unsigned long long s = 0;
    for (int r = 0; r < NREP; r++) s += hist[((size_t)r << 16) + bin];
    merged[bin] = s;
    local += s;
  }
  for (int off = 32; off > 0; off >>= 1) local += __shfl_down(local, off, 64);
  __shared__ unsigned long long red[4];
  if ((tid & 63) == 0) red[tid >> 6] = local;
  __syncthreads();
  if (tid == 0) blockTot[blk] = red[0] + red[1] + red[2] + red[3];
}

// ---- final: 2-level scan over 65536 bins; interpolated boundary; outputs ----
__global__ __launch_bounds__(256) void k_final(
    const unsigned long long* __restrict__ merged,
    const unsigned long long* __restrict__ blockTot,
    const Ctl* __restrict__ ctl, float* __restrict__ out) {
  __shared__ unsigned long long sb[64];
  __shared__ unsigned long long scan2[256];
  __shared__ int sBstar;
  __shared__ unsigned long long sPrefix;
  __shared__ double sNeg;
  int tid = threadIdx.x;
  unsigned rank = 3u * ctl->pnum;

  if (tid < 64) sb[tid] = blockTot[tid];
  if (tid == 0) { sBstar = -1; sNeg = 0.0; sPrefix = 0; }
  __syncthreads();
  if (tid == 0 && rank > 0) {
    unsigned long long pre = 0;
    for (int i = 0; i < 64; i++) {
      unsigned long long h = sb[i];
      unsigned c0 = (unsigned)(pre >> 44);
      unsigned c1 = (unsigned)((pre + h) >> 44);
      if (c0 < rank && c1 >= rank) { sBstar = i; sPrefix = pre; break; }
      pre += h;
    }
  }
  __syncthreads();

  int Bs = sBstar;
  if (Bs >= 0) {
    unsigned long long h4[4];
    unsigned long long s = 0;
    int base = Bs * 1024 + tid * 4;
    for (int j = 0; j < 4; j++) { h4[j] = merged[base + j]; s += h4[j]; }
    scan2[tid] = s;
    __syncthreads();
    for (int off = 1; off < 256; off <<= 1) {
      unsigned long long add = (tid >= off) ? scan2[tid - off] : 0ull;
      __syncthreads();
      scan2[tid] += add;
      __syncthreads();
    }
    unsigned long long cum = scan2[tid] - s + sPrefix;
    for (int j = 0; j < 4; j++) {
      unsigned c0 = (unsigned)(cum >> 44);
      unsigned c1 = (unsigned)((cum + h4[j]) >> 44);
      if (c0 < rank && c1 >= rank) {
        unsigned long long fixBelow = cum & FIXMASK;
        unsigned r = rank - c0;
        unsigned t1 = (unsigned)(base + j);
        float ceEdge = -key2f(t1 << 16);
        sNeg = (double)fixBelow / 262144.0 + (double)r * (double)ceEdge;
      }
      cum += h4[j];
    }
  }
  __syncthreads();
  if (tid == 0) {
    unsigned P = ctl->pnum;
    float negSum = (float)sNeg;
    out[0] = (ctl->posCE + negSum) / (float)max(4u * P, 1u);
    out[1] = ctl->bboxNum / (float)max(4u * ctl->validCount, 1u);
  }
}

extern "C" void kernel_launch(void* const* d_in, const int* in_sizes, int n_in,
                              void* d_out, int out_size, void* d_ws, size_t ws_size,
                              hipStream_t stream) {
  const float* conf = (const float*)d_in[0];
  const float* bbox = (const float*)d_in[1];
  const float* target = (const float*)d_in[2];
  const float* pred = (const float*)d_in[3];
  float* out = (float*)d_out;

  char* ws = (char*)d_ws;
  unsigned long long* hist = (unsigned long long*)ws;          // NREP*NB16 u64 = 2 MB
  size_t off = (size_t)NREP * NB16 * 8;
  unsigned long long* merged = (unsigned long long*)(ws + off); off += (size_t)NB16 * 8;
  unsigned long long* blockTot = (unsigned long long*)(ws + off); off += 64 * 8;
  Ctl* ctl = (Ctl*)(ws + off); off += sizeof(Ctl);

  k_zero<<<512, 256, 0, stream>>>(hist, ctl);
  k_main<<<dim3((N + 255) / 256, B), 256, 0, stream>>>(conf, bbox, target, pred, hist, ctl);
  k_merge<<<64, 256, 0, stream>>>(hist, merged, blockTot);
  k_final<<<1, 256, 0, stream>>>(merged, blockTot, ctl, out);
}

// Round 4
// 53.552 us; speedup vs baseline: 2.3535x; 2.3535x over previous
//
#include <hip/hip_runtime.h>

constexpr int B = 64, N = 8732, C = 21, M = 16;
constexpr int BN = B * N;             // 558848
constexpr int TROW = 1 + 6 * M;       // 97
constexpr int NBIN = 4096;
constexpr int NSLAB = 8;              // level-1 slab replicas
constexpr int R2 = 2;                 // level-2 replicas
constexpr int BPB = 5;                // blocks per batch in k_main
constexpr int STAGE_ROWS = 256;
constexpr int STAGES = 8;             // 2048 rows per block
constexpr float FSCALE = 262144.0f;   // 2^18 fixed-point for CE sums
constexpr unsigned long long CNT1 = 1ull << 44;
constexpr unsigned long long FIXMASK = (1ull << 44) - 1;

struct Sc {
  unsigned t1, r1;
  unsigned long long fixBelow1;
  float pnum, validCnt, posCE, bboxNum;
  unsigned rank;
};

__device__ __forceinline__ unsigned f2key(float f) {
  unsigned u = __float_as_uint(f);
  return (u & 0x80000000u) ? ~u : (u | 0x80000000u);
}
__device__ __forceinline__ float key2f(unsigned k) {
  unsigned u = (k & 0x80000000u) ? (k ^ 0x80000000u) : ~k;
  return __uint_as_float(u);
}

// ---- zero the 8 level-1 slabs (256 KB) ----
__global__ __launch_bounds__(256) void k_zero(unsigned long long* __restrict__ slab1) {
  int idx = blockIdx.x * 256 + threadIdx.x;   // 128 blocks * 256 = 32768 = NSLAB*NBIN
  slab1[idx] = 0ull;
}

// ---- main: logp0 per anchor -> keys + LDS hist -> slab merge; fused targets ----
__global__ __launch_bounds__(256) void k_main(
    const float* __restrict__ conf, const float* __restrict__ bbox,
    const float* __restrict__ target, const float* __restrict__ pred,
    unsigned* __restrict__ keys, unsigned long long* __restrict__ slab1,
    float4* __restrict__ batchCtl) {
  __shared__ __align__(16) float srow[STAGE_ROWS * C];   // 21504 B
  __shared__ unsigned long long shist[NBIN];             // 32768 B
  __shared__ int sk[M];
  int b = blockIdx.y, bx = blockIdx.x, tid = threadIdx.x;

  for (int i = tid; i < NBIN; i += 256) shist[i] = 0ull;
  const float* tr = target + (size_t)b * TROW;
  if (tid < M) {
    int num = (int)tr[0];
    sk[tid] = (tid < num) ? (int)tr[1 + 6 * tid + 5] : -1;
  }
  __syncthreads();

  int n0 = bx * (STAGE_ROWS * STAGES);
  int nEnd = min(n0 + STAGE_ROWS * STAGES, N);
  for (int s0 = n0; s0 < nEnd; s0 += STAGE_ROWS) {
    int rows = min(STAGE_ROWS, nEnd - s0);
    const float* g = conf + ((size_t)b * N + s0) * C;
    int nf = rows * C;
    int nf4 = nf >> 2;
    const float4* g4 = (const float4*)g;
    float4* s4 = (float4*)srow;
    for (int i = tid; i < nf4; i += 256) s4[i] = g4[i];
    for (int i = nf4 * 4 + tid; i < nf; i += 256) srow[i] = g[i];
    __syncthreads();
    if (tid < rows) {
      int n = s0 + tid;
      const float* x = srow + tid * C;
      float mx = x[0];
      for (int c = 1; c < C; c++) mx = fmaxf(mx, x[c]);
      float sum = 0.f;
      for (int c = 0; c < C; c++) sum += __expf(x[c] - mx);
      float logp0 = x[0] - mx - __logf(sum);
      bool asg = false;
      for (int j = 0; j < M; j++) asg |= (sk[j] == n);
      unsigned key = 0xFFFFFFFFu;
      if (!asg) {
        key = f2key(logp0);
        float ce = -logp0;
        atomicAdd(&shist[key >> 20],
                  CNT1 | (unsigned long long)(ce * FSCALE + 0.5f));
      }
      keys[(size_t)b * N + n] = key;
    }
    __syncthreads();
  }

  // merge LDS hist into one of 8 slabs (per-line chains <= ~320, hidden)
  unsigned long long* sg = slab1 + ((size_t)((b * BPB + bx) & (NSLAB - 1)) * NBIN);
  for (int i = tid; i < NBIN; i += 256) {
    unsigned long long v = shist[i];
    if (v) atomicAdd(&sg[i], v);
  }

  // fused per-batch target processing -> plain write of per-batch partials
  if (bx == 0) {
    float myValid = 0.f, myPos = 0.f, myCE = 0.f, mySL = 0.f;
    if (tid < M && sk[tid] >= 0) {
      const float* e = tr + 1 + 6 * tid;
      int cls = (int)e[0];
      float tx1 = e[1], ty1 = e[2], tx2 = e[3], ty2 = e[4];
      int k = sk[tid];
      float p0 = pred[k * 4 + 0], p1 = pred[k * 4 + 1];
      float p2 = pred[k * 4 + 2], p3 = pred[k * 4 + 3];
      float pw = p2 - p0, ph = p3 - p1;
      float pcx = (p0 + p2) * 0.5f, pcy = (p1 + p3) * 0.5f;
      float tw = tx2 - tx1, th = ty2 - ty1;
      float tcx = (tx1 + tx2) * 0.5f, tcy = (ty1 + ty2) * 0.5f;
      float ebv[4];
      ebv[0] = (tcx - pcx) / pw;
      ebv[1] = (tcy - pcy) / ph;
      ebv[2] = __logf(tw / pw);
      ebv[3] = __logf(th / ph);
      const float* bo = bbox + ((size_t)b * N + k) * 4;
      float sl = 0.f;
      for (int j = 0; j < 4; j++) {
        float d = bo[j] - ebv[j];
        float ad = fabsf(d);
        sl += (ad < 1.f) ? 0.5f * d * d : ad - 0.5f;
      }
      myValid = 1.f; mySL = sl;
      if (cls > 0) {
        const float* x = conf + ((size_t)b * N + k) * C;
        float mx = x[0];
        for (int c = 1; c < C; c++) mx = fmaxf(mx, x[c]);
        float s = 0.f;
        for (int c = 0; c < C; c++) s += __expf(x[c] - mx);
        float lp = x[cls] - mx - __logf(s);
        myPos = 1.f; myCE = -lp;
      }
    }
    if (tid < 64) {
      for (int off = 32; off; off >>= 1) {
        myValid += __shfl_down(myValid, off, 64);
        myPos   += __shfl_down(myPos, off, 64);
        myCE    += __shfl_down(myCE, off, 64);
        mySL    += __shfl_down(mySL, off, 64);
      }
      if (tid == 0) batchCtl[b] = make_float4(myPos, myValid, myCE, mySL);
    }
  }
}

// ---- scan1: reduce 8 slabs, scan 4096 bins, find t1/r1/exact-below; zero merged2 ----
__global__ __launch_bounds__(1024) void k_scan1(
    const unsigned long long* __restrict__ slab1,
    const float4* __restrict__ batchCtl,
    unsigned long long* __restrict__ merged2, Sc* __restrict__ sc) {
  __shared__ unsigned long long sm[NBIN];
  __shared__ unsigned long long sscan[1024];
  __shared__ unsigned srank;
  int tid = threadIdx.x;

  for (int i = tid; i < R2 * NBIN; i += 1024) merged2[i] = 0ull;

  if (tid < 64) {
    float4 v = batchCtl[tid];
    float p = v.x, va = v.y, ce = v.z, sl = v.w;
    for (int off = 32; off; off >>= 1) {
      p  += __shfl_down(p, off, 64);
      va += __shfl_down(va, off, 64);
      ce += __shfl_down(ce, off, 64);
      sl += __shfl_down(sl, off, 64);
    }
    if (tid == 0) {
      sc->pnum = p; sc->validCnt = va; sc->posCE = ce; sc->bboxNum = sl;
      unsigned rank = 3u * (unsigned)(p + 0.5f);
      sc->rank = rank; srank = rank;
      sc->t1 = 0xFFFFFFFFu; sc->r1 = 0; sc->fixBelow1 = 0ull;
    }
  }

  for (int k = 0; k < 4; k++) {
    int bin = tid + k * 1024;
    unsigned long long v = 0ull;
    for (int s = 0; s < NSLAB; s++) v += slab1[(size_t)s * NBIN + bin];
    sm[bin] = v;
  }
  __syncthreads();

  unsigned long long part = sm[tid * 4] + sm[tid * 4 + 1] + sm[tid * 4 + 2] + sm[tid * 4 + 3];
  sscan[tid] = part;
  __syncthreads();
  for (int off = 1; off < 1024; off <<= 1) {
    unsigned long long add = (tid >= off) ? sscan[tid - off] : 0ull;
    __syncthreads();
    sscan[tid] += add;
    __syncthreads();
  }

  unsigned rank = srank;
  if (rank) {
    unsigned long long cum = sscan[tid] - part;
    for (int j = 0; j < 4; j++) {
      unsigned long long h = sm[tid * 4 + j];
      unsigned c0 = (unsigned)(cum >> 44);
      unsigned c1 = (unsigned)((cum + h) >> 44);
      if (c0 < rank && c1 >= rank) {
        sc->t1 = (unsigned)(tid * 4 + j);
        sc->r1 = rank - c0;
        sc->fixBelow1 = cum & FIXMASK;
      }
      cum += h;
    }
  }
}

// ---- pass2: re-read keys, LDS hist of bin-t1 candidates on bits[19:8] ----
__global__ __launch_bounds__(256) void k_pass2(
    const unsigned* __restrict__ keys, const Sc* __restrict__ sc,
    unsigned long long* __restrict__ merged2) {
  __shared__ unsigned long long lh[NBIN];
  int tid = threadIdx.x;
  unsigned t1 = sc->t1;
  for (int i = tid; i < NBIN; i += 256) lh[i] = 0ull;
  __syncthreads();
  int gtid = blockIdx.x * 256 + tid;
  const uint4* k4 = (const uint4*)keys;
  for (int i = gtid; i < BN / 4; i += 64 * 256) {
    uint4 v = k4[i];
    unsigned a0 = v.x, a1 = v.y, a2 = v.z, a3 = v.w;
    unsigned arr[4] = {a0, a1, a2, a3};
    for (int j = 0; j < 4; j++) {
      unsigned key = arr[j];
      if ((key >> 20) == t1) {
        float ce = -key2f(key);
        atomicAdd(&lh[(key >> 8) & 0xFFFu],
                  CNT1 | (unsigned long long)(ce * FSCALE + 0.5f));
      }
    }
  }
  __syncthreads();
  unsigned long long* mg = merged2 + ((size_t)(blockIdx.x & (R2 - 1)) * NBIN);
  for (int i = tid; i < NBIN; i += 256) {
    unsigned long long v = lh[i];
    if (v) atomicAdd(&mg[i], v);
  }
}

// ---- final: scan level-2, exact within-bin prefix + r2*edge tail; outputs ----
__global__ __launch_bounds__(256) void k_final(
    const unsigned long long* __restrict__ merged2, const Sc* __restrict__ sc,
    float* __restrict__ out) {
  __shared__ unsigned long long sm[NBIN];
  __shared__ unsigned long long sscan[256];
  __shared__ double sNeg2;
  int tid = threadIdx.x;
  if (tid == 0) sNeg2 = 0.0;
  for (int k = 0; k < 16; k++) {
    int bin = tid + k * 256;
    sm[bin] = merged2[bin] + merged2[NBIN + bin];
  }
  __syncthreads();
  unsigned long long part = 0ull;
  for (int j = 0; j < 16; j++) part += sm[tid * 16 + j];
  sscan[tid] = part;
  __syncthreads();
  for (int off = 1; off < 256; off <<= 1) {
    unsigned long long add = (tid >= off) ? sscan[tid - off] : 0ull;
    __syncthreads();
    sscan[tid] += add;
    __syncthreads();
  }
  unsigned r1 = sc->r1, t1 = sc->t1;
  if (r1) {
    unsigned long long cum = sscan[tid] - part;
    for (int j = 0; j < 16; j++) {
      unsigned long long h = sm[tid * 16 + j];
      unsigned c0 = (unsigned)(cum >> 44);
      unsigned c1 = (unsigned)((cum + h) >> 44);
      if (c0 < r1 && c1 >= r1) {
        unsigned t2 = (unsigned)(tid * 16 + j);
        unsigned r2v = r1 - c0;
        unsigned long long fixB2 = cum & FIXMASK;
        float ceEdge = -key2f((t1 << 20) | (t2 << 8));
        sNeg2 = (double)(sc->fixBelow1 + fixB2) / 262144.0 +
                (double)r2v * (double)ceEdge;
      }
      cum += h;
    }
  }
  __syncthreads();
  if (tid == 0) {
    float P = sc->pnum;
    float negSum = (float)sNeg2;
    out[0] = (sc->posCE + negSum) / fmaxf(4.0f * P, 1.0f);
    out[1] = sc->bboxNum / fmaxf(4.0f * sc->validCnt, 1.0f);
  }
}

extern "C" void kernel_launch(void* const* d_in, const int* in_sizes, int n_in,
                              void* d_out, int out_size, void* d_ws, size_t ws_size,
                              hipStream_t stream) {
  const float* conf = (const float*)d_in[0];
  const float* bbox = (const float*)d_in[1];
  const float* target = (const float*)d_in[2];
  const float* pred = (const float*)d_in[3];
  float* out = (float*)d_out;

  char* ws = (char*)d_ws;
  unsigned* keys = (unsigned*)ws;
  size_t off = (size_t)BN * 4;                                   // 2,235,392
  unsigned long long* slab1 = (unsigned long long*)(ws + off); off += (size_t)NSLAB * NBIN * 8;
  unsigned long long* merged2 = (unsigned long long*)(ws + off); off += (size_t)R2 * NBIN * 8;
  float4* batchCtl = (float4*)(ws + off); off += 64 * 16;
  Sc* sc = (Sc*)(ws + off); off += sizeof(Sc);

  k_zero<<<dim3(NSLAB * NBIN / 256), 256, 0, stream>>>(slab1);
  k_main<<<dim3(BPB, B), 256, 0, stream>>>(conf, bbox, target, pred, keys, slab1, batchCtl);
  k_scan1<<<1, 1024, 0, stream>>>(slab1, batchCtl, merged2, sc);
  k_pass2<<<64, 256, 0, stream>>>(keys, sc, merged2);
  k_final<<<1, 256, 0, stream>>>(merged2, sc, out);
}

// Round 5
// 43.258 us; speedup vs baseline: 2.9135x; 1.2379x over previous
//
#include <hip/hip_runtime.h>

constexpr int B = 64, N = 8732, C = 21, M = 16;
constexpr int BN = B * N;             // 558848
constexpr int TROW = 1 + 6 * M;       // 97
constexpr int NB1 = 2048;             // level-1 bins (key >> 21)
constexpr int NB2 = 4096;             // level-2 bins (key >> 9) & 0xFFF
constexpr int NSLAB = 8;              // level-1 slab replicas
constexpr int R2 = 2;                 // level-2 replicas
constexpr int ROWS_PB = 256;          // rows per k_main block
constexpr int BPB = (N + ROWS_PB - 1) / ROWS_PB;  // 35 blocks per batch
constexpr float FSCALE = 262144.0f;   // 2^18 fixed-point for CE sums
constexpr unsigned long long CNT1 = 1ull << 44;
constexpr unsigned long long FIXMASK = (1ull << 44) - 1;

struct Sc {
  unsigned t1, r1;
  unsigned long long fixBelow1;
  float pnum, validCnt, posCE, bboxNum;
  unsigned rank;
};

__device__ __forceinline__ unsigned f2key(float f) {
  unsigned u = __float_as_uint(f);
  return (u & 0x80000000u) ? ~u : (u | 0x80000000u);
}
__device__ __forceinline__ float key2f(unsigned k) {
  unsigned u = (k & 0x80000000u) ? (k ^ 0x80000000u) : ~k;
  return __uint_as_float(u);
}

// ---- zero the level-1 slabs (8 * 2048 u64 = 128 KB) ----
__global__ __launch_bounds__(256) void k_zero(unsigned long long* __restrict__ slab1) {
  int idx = blockIdx.x * 256 + threadIdx.x;   // 64 blocks * 256 = 16384
  slab1[idx] = 0ull;
}

// ---- main: logp0 per anchor -> keys + LDS hist -> slab merge; fused targets ----
__global__ __launch_bounds__(256) void k_main(
    const float* __restrict__ conf, const float* __restrict__ bbox,
    const float* __restrict__ target, const float* __restrict__ pred,
    unsigned* __restrict__ keys, unsigned long long* __restrict__ slab1,
    float4* __restrict__ batchCtl) {
  __shared__ __align__(16) float srow[ROWS_PB * C];      // 21504 B
  __shared__ unsigned long long shist[NB1];              // 16384 B
  __shared__ int sk[M];
  int b = blockIdx.y, bx = blockIdx.x, tid = threadIdx.x;

  for (int i = tid; i < NB1; i += 256) shist[i] = 0ull;
  const float* tr = target + (size_t)b * TROW;
  if (tid < M) {
    int num = (int)tr[0];
    sk[tid] = (tid < M && tid < num) ? (int)tr[1 + 6 * tid + 5] : -1;
  }
  __syncthreads();

  int n0 = bx * ROWS_PB;
  int rows = min(ROWS_PB, N - n0);
  const float* g = conf + ((size_t)b * N + n0) * C;
  int nf = rows * C;
  int nf4 = nf >> 2;
  const float4* g4 = (const float4*)g;
  float4* s4 = (float4*)srow;
  for (int i = tid; i < nf4; i += 256) s4[i] = g4[i];
  for (int i = nf4 * 4 + tid; i < nf; i += 256) srow[i] = g[i];
  __syncthreads();

  if (tid < rows) {
    int n = n0 + tid;
    const float* x = srow + tid * C;
    float mx = x[0];
    for (int c = 1; c < C; c++) mx = fmaxf(mx, x[c]);
    float sum = 0.f;
    for (int c = 0; c < C; c++) sum += __expf(x[c] - mx);
    float logp0 = x[0] - mx - __logf(sum);
    bool asg = false;
    for (int j = 0; j < M; j++) asg |= (sk[j] == n);
    unsigned key = 0xFFFFFFFFu;
    if (!asg) {
      key = f2key(logp0);
      float ce = -logp0;
      atomicAdd(&shist[key >> 21],
                CNT1 | (unsigned long long)(ce * FSCALE + 0.5f));
    }
    keys[(size_t)b * N + n] = key;
  }
  __syncthreads();

  // merge LDS hist into one of 8 slabs; <=256 nonzero bins per block
  unsigned long long* sg = slab1 + ((size_t)((b * BPB + bx) & (NSLAB - 1)) * NB1);
  for (int i = tid; i < NB1; i += 256) {
    unsigned long long v = shist[i];
    if (v) atomicAdd(&sg[i], v);
  }

  // fused per-batch target processing -> plain write of per-batch partials
  if (bx == 0) {
    float myValid = 0.f, myPos = 0.f, myCE = 0.f, mySL = 0.f;
    if (tid < M && sk[tid] >= 0) {
      const float* e = tr + 1 + 6 * tid;
      int cls = (int)e[0];
      float tx1 = e[1], ty1 = e[2], tx2 = e[3], ty2 = e[4];
      int k = sk[tid];
      float p0 = pred[k * 4 + 0], p1 = pred[k * 4 + 1];
      float p2 = pred[k * 4 + 2], p3 = pred[k * 4 + 3];
      float pw = p2 - p0, ph = p3 - p1;
      float pcx = (p0 + p2) * 0.5f, pcy = (p1 + p3) * 0.5f;
      float tw = tx2 - tx1, th = ty2 - ty1;
      float tcx = (tx1 + tx2) * 0.5f, tcy = (ty1 + ty2) * 0.5f;
      float ebv[4];
      ebv[0] = (tcx - pcx) / pw;
      ebv[1] = (tcy - pcy) / ph;
      ebv[2] = __logf(tw / pw);
      ebv[3] = __logf(th / ph);
      const float* bo = bbox + ((size_t)b * N + k) * 4;
      float sl = 0.f;
      for (int j = 0; j < 4; j++) {
        float d = bo[j] - ebv[j];
        float ad = fabsf(d);
        sl += (ad < 1.f) ? 0.5f * d * d : ad - 0.5f;
      }
      myValid = 1.f; mySL = sl;
      if (cls > 0) {
        const float* x = conf + ((size_t)b * N + k) * C;
        float mx = x[0];
        for (int c = 1; c < C; c++) mx = fmaxf(mx, x[c]);
        float s = 0.f;
        for (int c = 0; c < C; c++) s += __expf(x[c] - mx);
        float lp = x[cls] - mx - __logf(s);
        myPos = 1.f; myCE = -lp;
      }
    }
    if (tid < 64) {
      for (int off = 32; off; off >>= 1) {
        myValid += __shfl_down(myValid, off, 64);
        myPos   += __shfl_down(myPos, off, 64);
        myCE    += __shfl_down(myCE, off, 64);
        mySL    += __shfl_down(mySL, off, 64);
      }
      if (tid == 0) batchCtl[b] = make_float4(myPos, myValid, myCE, mySL);
    }
  }
}

// ---- scan1: reduce slabs, scan 2048 bins, find t1/r1/exact-below; zero merged2 ----
__global__ __launch_bounds__(256) void k_scan1(
    const unsigned long long* __restrict__ slab1,
    const float4* __restrict__ batchCtl,
    unsigned long long* __restrict__ merged2, Sc* __restrict__ sc) {
  __shared__ unsigned long long sm[NB1];
  __shared__ unsigned long long sscan[256];
  __shared__ unsigned srank;
  int tid = threadIdx.x;

  for (int i = tid; i < R2 * NB2; i += 256) merged2[i] = 0ull;

  if (tid < 64) {
    float4 v = batchCtl[tid];
    float p = v.x, va = v.y, ce = v.z, sl = v.w;
    for (int off = 32; off; off >>= 1) {
      p  += __shfl_down(p, off, 64);
      va += __shfl_down(va, off, 64);
      ce += __shfl_down(ce, off, 64);
      sl += __shfl_down(sl, off, 64);
    }
    if (tid == 0) {
      sc->pnum = p; sc->validCnt = va; sc->posCE = ce; sc->bboxNum = sl;
      unsigned rank = 3u * (unsigned)(p + 0.5f);
      sc->rank = rank; srank = rank;
      sc->t1 = 0xFFFFFFFFu; sc->r1 = 0; sc->fixBelow1 = 0ull;
    }
  }

  for (int j = 0; j < NB1 / 256; j++) {
    int bin = tid + j * 256;
    unsigned long long v = 0ull;
    for (int s = 0; s < NSLAB; s++) v += slab1[(size_t)s * NB1 + bin];
    sm[bin] = v;
  }
  __syncthreads();

  unsigned long long part = 0ull;
  for (int j = 0; j < 8; j++) part += sm[tid * 8 + j];
  sscan[tid] = part;
  __syncthreads();
  for (int off = 1; off < 256; off <<= 1) {
    unsigned long long add = (tid >= off) ? sscan[tid - off] : 0ull;
    __syncthreads();
    sscan[tid] += add;
    __syncthreads();
  }

  unsigned rank = srank;
  if (rank) {
    unsigned long long cum = sscan[tid] - part;
    for (int j = 0; j < 8; j++) {
      unsigned long long h = sm[tid * 8 + j];
      unsigned c0 = (unsigned)(cum >> 44);
      unsigned c1 = (unsigned)((cum + h) >> 44);
      if (c0 < rank && c1 >= rank) {
        sc->t1 = (unsigned)(tid * 8 + j);
        sc->r1 = rank - c0;
        sc->fixBelow1 = cum & FIXMASK;
      }
      cum += h;
    }
  }
}

// ---- pass2: re-read keys, LDS hist of bin-t1 candidates on bits [20:9] ----
__global__ __launch_bounds__(256) void k_pass2(
    const unsigned* __restrict__ keys, const Sc* __restrict__ sc,
    unsigned long long* __restrict__ merged2) {
  __shared__ unsigned long long lh[NB2];
  int tid = threadIdx.x;
  unsigned t1 = sc->t1;
  for (int i = tid; i < NB2; i += 256) lh[i] = 0ull;
  __syncthreads();
  int gtid = blockIdx.x * 256 + tid;
  const uint4* k4 = (const uint4*)keys;
  for (int i = gtid; i < BN / 4; i += 64 * 256) {
    uint4 v = k4[i];
    unsigned arr[4] = {v.x, v.y, v.z, v.w};
    for (int j = 0; j < 4; j++) {
      unsigned key = arr[j];
      if ((key >> 21) == t1) {
        float ce = -key2f(key);
        atomicAdd(&lh[(key >> 9) & 0xFFFu],
                  CNT1 | (unsigned long long)(ce * FSCALE + 0.5f));
      }
    }
  }
  __syncthreads();
  unsigned long long* mg = merged2 + ((size_t)(blockIdx.x & (R2 - 1)) * NB2);
  for (int i = tid; i < NB2; i += 256) {
    unsigned long long v = lh[i];
    if (v) atomicAdd(&mg[i], v);
  }
}

// ---- final: scan level-2, exact within-bin prefix + tail; outputs ----
__global__ __launch_bounds__(256) void k_final(
    const unsigned long long* __restrict__ merged2, const Sc* __restrict__ sc,
    float* __restrict__ out) {
  __shared__ unsigned long long sm[NB2];
  __shared__ unsigned long long sscan[256];
  __shared__ double sNeg2;
  int tid = threadIdx.x;
  if (tid == 0) sNeg2 = 0.0;
  for (int k = 0; k < NB2 / 256; k++) {
    int bin = tid + k * 256;
    sm[bin] = merged2[bin] + merged2[NB2 + bin];
  }
  __syncthreads();
  unsigned long long part = 0ull;
  for (int j = 0; j < 16; j++) part += sm[tid * 16 + j];
  sscan[tid] = part;
  __syncthreads();
  for (int off = 1; off < 256; off <<= 1) {
    unsigned long long add = (tid >= off) ? sscan[tid - off] : 0ull;
    __syncthreads();
    sscan[tid] += add;
    __syncthreads();
  }
  unsigned r1 = sc->r1, t1 = sc->t1;
  if (r1) {
    unsigned long long cum = sscan[tid] - part;
    for (int j = 0; j < 16; j++) {
      unsigned long long h = sm[tid * 16 + j];
      unsigned c0 = (unsigned)(cum >> 44);
      unsigned c1 = (unsigned)((cum + h) >> 44);
      if (c0 < r1 && c1 >= r1) {
        unsigned t2 = (unsigned)(tid * 16 + j);
        unsigned r2v = r1 - c0;
        unsigned long long fixB2 = cum & FIXMASK;
        float ceEdge = -key2f((t1 << 21) | (t2 << 9));
        sNeg2 = (double)(sc->fixBelow1 + fixB2) / 262144.0 +
                (double)r2v * (double)ceEdge;
      }
      cum += h;
    }
  }
  __syncthreads();
  if (tid == 0) {
    float P = sc->pnum;
    float negSum = (float)sNeg2;
    out[0] = (sc->posCE + negSum) / fmaxf(4.0f * P, 1.0f);
    out[1] = sc->bboxNum / fmaxf(4.0f * sc->validCnt, 1.0f);
  }
}

extern "C" void kernel_launch(void* const* d_in, const int* in_sizes, int n_in,
                              void* d_out, int out_size, void* d_ws, size_t ws_size,
                              hipStream_t stream) {
  const float* conf = (const float*)d_in[0];
  const float* bbox = (const float*)d_in[1];
  const float* target = (const float*)d_in[2];
  const float* pred = (const float*)d_in[3];
  float* out = (float*)d_out;

  char* ws = (char*)d_ws;
  unsigned* keys = (unsigned*)ws;
  size_t off = (size_t)BN * 4;
  unsigned long long* slab1 = (unsigned long long*)(ws + off); off += (size_t)NSLAB * NB1 * 8;
  unsigned long long* merged2 = (unsigned long long*)(ws + off); off += (size_t)R2 * NB2 * 8;
  float4* batchCtl = (float4*)(ws + off); off += 64 * 16;
  Sc* sc = (Sc*)(ws + off); off += sizeof(Sc);

  k_zero<<<dim3(NSLAB * NB1 / 256), 256, 0, stream>>>(slab1);
  k_main<<<dim3(BPB, B), 256, 0, stream>>>(conf, bbox, target, pred, keys, slab1, batchCtl);
  k_scan1<<<1, 256, 0, stream>>>(slab1, batchCtl, merged2, sc);
  k_pass2<<<64, 256, 0, stream>>>(keys, sc, merged2);
  k_final<<<1, 256, 0, stream>>>(merged2, sc, out);
}